// Round 13
// baseline (236.537 us; speedup 1.0000x reference)
//
#include <hip/hip_runtime.h>

#define NN 100000
#define NE 1600000
#define NBKT 196                 // ceil(NN / 512)
#define CAP 12288                // per-bucket csr capacity (max ~8600 expected)
#define EPB 2048                 // edges per block in binning pass
#define ABLK ((NE + EPB - 1) / EPB)  // 782
typedef unsigned short u16;
typedef unsigned int u32;

typedef __attribute__((ext_vector_type(8))) short short8v;
typedef __attribute__((ext_vector_type(4))) float f32x4;

// ---- bf16 helpers (round-to-nearest-even) ----
__device__ __forceinline__ u32 f2bf(float f) {
    u32 u = __float_as_uint(f);
    return (u + 0x7fffu + ((u >> 16) & 1u)) >> 16;
}
__device__ __forceinline__ u32 pack2(float a, float b) {
    return f2bf(a) | (f2bf(b) << 16);
}
__device__ __forceinline__ void accum8(float* a, uint4 u, float w) {
    a[0] += __uint_as_float(u.x << 16) * w;
    a[1] += __uint_as_float(u.x & 0xffff0000u) * w;
    a[2] += __uint_as_float(u.y << 16) * w;
    a[3] += __uint_as_float(u.y & 0xffff0000u) * w;
    a[4] += __uint_as_float(u.z << 16) * w;
    a[5] += __uint_as_float(u.z & 0xffff0000u) * w;
    a[6] += __uint_as_float(u.w << 16) * w;
    a[7] += __uint_as_float(u.w & 0xffff0000u) * w;
}

// ---------------- bin edges into fixed-capacity buckets ---------------------
__global__ __launch_bounds__(256) void kA_bin(const int* __restrict__ src,
                                              const int* __restrict__ dst,
                                              int* __restrict__ gcnt,
                                              u32* __restrict__ binned) {
    __shared__ int bc[NBKT];
    __shared__ int cbase[NBKT];
    const int tid = threadIdx.x;
    for (int i = tid; i < NBKT; i += 256) bc[i] = 0;
    __syncthreads();
    const int e0 = blockIdx.x * EPB;
#pragma unroll
    for (int i = 0; i < EPB / 256; ++i) {
        const int e = e0 + i * 256 + tid;
        if (e < NE) atomicAdd(&bc[dst[e] >> 9], 1);
    }
    __syncthreads();
    for (int i = tid; i < NBKT; i += 256)
        cbase[i] = bc[i] ? atomicAdd(&gcnt[i], bc[i]) : 0;
    __syncthreads();
    for (int i = tid; i < NBKT; i += 256) bc[i] = 0;  // reuse as cursor
    __syncthreads();
#pragma unroll
    for (int i = 0; i < EPB / 256; ++i) {
        const int e = e0 + i * 256 + tid;
        if (e < NE) {
            const int d = dst[e];
            const int bkt = d >> 9;
            const int p = atomicAdd(&bc[bkt], 1);
            binned[bkt * CAP + cbase[bkt] + p] = ((u32)src[e] << 9) | (u32)(d & 511);
        }
    }
}

// ---------------- per-bucket: counts -> off2/dinv, fill csr, cvt x ----------
__global__ __launch_bounds__(256) void kB_fill(const u32* __restrict__ binned,
                                               const int* __restrict__ gcnt,
                                               int2* __restrict__ off2,
                                               float* __restrict__ dinv,
                                               int* __restrict__ csr,
                                               const float* __restrict__ x,
                                               u16* __restrict__ xb) {
    __shared__ int lcnt[512];
    __shared__ int lpos[512];
    __shared__ float sdinv[512];
    __shared__ int ws[4];
    const int b = blockIdx.x;
    const int tid = threadIdx.x;
    const int cnt = gcnt[b];
    const int base0 = b * CAP;
    const int node0 = b << 9;
    lcnt[tid] = 0;
    lcnt[tid + 256] = 0;
    __syncthreads();
    for (int e = tid; e < cnt; e += 256)
        atomicAdd(&lcnt[binned[base0 + e] & 511], 1);
    __syncthreads();
    const int c0 = lcnt[tid * 2], c1 = lcnt[tid * 2 + 1];
    const int s = c0 + c1;
    const int lane = tid & 63, w = tid >> 6;
    int incl = s;
#pragma unroll
    for (int o = 1; o < 64; o <<= 1) {
        const int u = __shfl_up(incl, o);
        if (lane >= o) incl += u;
    }
    if (lane == 63) ws[w] = incl;
    __syncthreads();
    int base = incl - s;
    for (int i = 0; i < w; ++i) base += ws[i];
    lpos[tid * 2] = base;
    lpos[tid * 2 + 1] = base + c0;
    const float d0 = rsqrtf(1.0f + (float)c0);
    const float d1 = rsqrtf(1.0f + (float)c1);
    sdinv[tid * 2] = d0;
    sdinv[tid * 2 + 1] = d1;
    const int n0 = node0 + tid * 2;
    if (n0 < NN) {
        off2[n0] = make_int2(base0 + base, base0 + base + c0);
        dinv[n0] = d0;
    }
    if (n0 + 1 < NN) {
        off2[n0 + 1] = make_int2(base0 + base + c0, base0 + base + c0 + c1);
        dinv[n0 + 1] = d1;
    }
    __syncthreads();
    for (int e = tid; e < cnt; e += 256) {
        const u32 u = binned[base0 + e];
        const int p = atomicAdd(&lpos[u & 511], 1);
        csr[base0 + p] = (int)(u >> 9);
    }
    // ---- fused cvt: x rows of this bucket -> bf16 pre-scaled by dinv ----
    const int nmax = min(512, NN - node0);
    for (int gi = tid; gi < nmax * 8; gi += 256) {
        const int nl = gi >> 3, ch = gi & 7;
        const float dr = sdinv[nl];
        const size_t xo = (size_t)(node0 + nl) * 64 + ch * 8;
        const float4 v0 = *(const float4*)&x[xo];
        const float4 v1 = *(const float4*)&x[xo + 4];
        uint4 o;
        o.x = pack2(v0.x * dr, v0.y * dr); o.y = pack2(v0.z * dr, v0.w * dr);
        o.z = pack2(v1.x * dr, v1.y * dr); o.w = pack2(v1.z * dr, v1.w * dr);
        *(uint4*)&xb[xo] = o;
    }
}

// ---------------- prep: WT1, WT2 (transposed bf16) + gcnt zero --------------
__global__ __launch_bounds__(256) void k_prep(const float* __restrict__ W1,
                                              const float* __restrict__ W2,
                                              u16* __restrict__ WT1,
                                              u16* __restrict__ WT2,
                                              int* __restrict__ gcnt) {
    const int i = blockIdx.x * 256 + threadIdx.x;
    if (i < 8192) {                       // W1: 64x128 -> WT1[128][64]
        const int k = i >> 7, c = i & 127;
        WT1[c * 64 + k] = (u16)f2bf(W1[i]);
    } else if (i < 24576) {               // W2: 128x128 -> WT2[128][128]
        const int i2 = i - 8192;
        const int k = i2 >> 7, c = i2 & 127;
        WT2[c * 128 + k] = (u16)f2bf(W2[i2]);
    } else if (i < 24576 + NBKT) {
        gcnt[i - 24576] = 0;
    }
}

// ---------------- fused, wave-independent: gather + MFMA + bias + LN + ReLU -
// Each wave owns 16 nodes: 3-deep pipelined gather -> private LDS slice
// (XOR-swizzled, no __syncthreads) -> 16x128xK MFMA -> in-wave LN -> write.
template<int K, bool FP32OUT, bool PRESCALE>
__global__ __launch_bounds__(256) void k_fused(const u16* __restrict__ A,
                                               const int2* __restrict__ off2,
                                               const int* __restrict__ csr,
                                               const float* __restrict__ dinv,
                                               const u16* __restrict__ WT,
                                               const float* __restrict__ bias,
                                               const float* __restrict__ g,
                                               const float* __restrict__ bt,
                                               void* __restrict__ outp) {
    constexpr int RB = K * 2;          // staged row bytes
    constexpr int SUBS = 512 / K;      // 8 (K=64) or 4 (K=128)
    constexpr int LSH = (K == 64) ? 7 : 8;
    __shared__ u16 As[4 * 16 * K];
    const int tid = threadIdx.x;
    const int wv = tid >> 6, lane = tid & 63;
    const int sub = lane / (64 / SUBS);
    const int l = lane & (64 / SUBS - 1);
    const char* Ab = (const char*)A + ((u32)l << 4);
    char* myAs = (char*)As + wv * 16 * RB;
    const int nodeBase = blockIdx.x * 64 + wv * 16;

    // ---- phase 1: gather 16 nodes (wave-private, no barrier) ----
    for (int i = 0; i < 16; ++i) {
        const int node = min(nodeBase + i, NN - 1);
        const float di = dinv[node];
        float a[8] = {};
        {
            const uint4 u = *(const uint4*)(Ab + ((u32)node << LSH));
            accum8(a, u, (sub == 0) ? 1.0f : 0.0f);
        }
        const int2 oe = off2[node];
        int base = oe.x;
        const int e1 = oe.y;
        u32 iA = 0, iB = 0, iC = 0;
        float vA = 0.f, vB = 0.f, vC = 0.f;
        if (base < e1) {
            const int eA = base + sub, eB = eA + SUBS, eC = eA + 2 * SUBS;
            iA = (u32)csr[min(eA, e1 - 1)];
            iB = (u32)csr[min(eB, e1 - 1)];
            iC = (u32)csr[min(eC, e1 - 1)];
            vA = (eA < e1) ? 1.f : 0.f;
            vB = (eB < e1) ? 1.f : 0.f;
            vC = (eC < e1) ? 1.f : 0.f;
        }
        while (base < e1) {
            const uint4 uA = *(const uint4*)(Ab + (iA << LSH));
            const uint4 uB = *(const uint4*)(Ab + (iB << LSH));
            const uint4 uC = *(const uint4*)(Ab + (iC << LSH));
            const float wA = vA, wB = vB, wC = vC;
            base += 3 * SUBS;
            if (base < e1) {
                const int eA = base + sub, eB = eA + SUBS, eC = eA + 2 * SUBS;
                iA = (u32)csr[min(eA, e1 - 1)];
                iB = (u32)csr[min(eB, e1 - 1)];
                iC = (u32)csr[min(eC, e1 - 1)];
                vA = (eA < e1) ? 1.f : 0.f;
                vB = (eB < e1) ? 1.f : 0.f;
                vC = (eC < e1) ? 1.f : 0.f;
            }
            accum8(a, uA, wA);
            accum8(a, uB, wB);
            accum8(a, uC, wC);
        }
#pragma unroll
        for (int t = 0; t < 8; ++t)
#pragma unroll
            for (int o = 64 / SUBS; o < 64; o <<= 1)
                a[t] += __shfl_xor(a[t], o);
        if (sub == 0) {
            uint4 o;
            o.x = pack2(a[0] * di, a[1] * di); o.y = pack2(a[2] * di, a[3] * di);
            o.z = pack2(a[4] * di, a[5] * di); o.w = pack2(a[6] * di, a[7] * di);
            *(uint4*)(myAs + i * RB + (((u32)l << 4) ^ ((u32)(i & 7) << 4))) = o;
        }
    }

    // ---- phase 2: 16 x 128 x K MFMA from private LDS ----
    const int lr = lane & 15, kg = lane >> 4;
    short8v af[K / 32];
#pragma unroll
    for (int kk = 0; kk < K / 32; ++kk)
        af[kk] = *(const short8v*)(myAs + lr * RB +
                                   ((u32)(kk * 64 + kg * 16) ^ ((u32)(lr & 7) << 4)));
    f32x4 acc[8];
#pragma unroll
    for (int nt = 0; nt < 8; ++nt) {
        acc[nt] = (f32x4){0.f, 0.f, 0.f, 0.f};
        const int col = nt * 16 + lr;
        short8v bf[K / 32];
#pragma unroll
        for (int kk = 0; kk < K / 32; ++kk)
            bf[kk] = *(const short8v*)&WT[col * K + kk * 32 + kg * 8];
#pragma unroll
        for (int kk = 0; kk < K / 32; ++kk)
            acc[nt] = __builtin_amdgcn_mfma_f32_16x16x32_bf16(af[kk], bf[kk], acc[nt], 0, 0, 0);
    }

    // ---- bias + in-wave LN stats (rows kg*4+j all live in-wave) ----
    float s1[4] = {0.f, 0.f, 0.f, 0.f};
    float s2[4] = {0.f, 0.f, 0.f, 0.f};
#pragma unroll
    for (int nt = 0; nt < 8; ++nt) {
        const float bvn = bias[nt * 16 + lr];
#pragma unroll
        for (int j = 0; j < 4; ++j) {
            const float v = acc[nt][j] + bvn;
            acc[nt][j] = v;
            s1[j] += v;
            s2[j] += v * v;
        }
    }
#pragma unroll
    for (int j = 0; j < 4; ++j)
#pragma unroll
        for (int o = 1; o < 16; o <<= 1) {
            s1[j] += __shfl_xor(s1[j], o);
            s2[j] += __shfl_xor(s2[j], o);
        }
    float mu4[4], rs4[4], dr4[4];
    int wr4[4];
#pragma unroll
    for (int j = 0; j < 4; ++j) {
        const int node = nodeBase + kg * 4 + j;
        wr4[j] = node < NN;
        const float mu = s1[j] * (1.0f / 128.0f);
        const float var = s2[j] * (1.0f / 128.0f) - mu * mu;
        mu4[j] = mu;
        rs4[j] = rsqrtf(var + 1e-5f);
        dr4[j] = PRESCALE ? dinv[min(node, NN - 1)] : 1.0f;
    }
#pragma unroll
    for (int nt = 0; nt < 8; ++nt) {
        const int col = nt * 16 + lr;
        const float gvn = g[col];
        const float tvn = bt[col];
#pragma unroll
        for (int j = 0; j < 4; ++j) {
            if (wr4[j]) {
                const int node = nodeBase + kg * 4 + j;
                const float y = fmaxf((acc[nt][j] - mu4[j]) * rs4[j] * gvn + tvn, 0.f) * dr4[j];
                if constexpr (FP32OUT)
                    ((float*)outp)[(size_t)node * 128 + col] = y;
                else
                    ((u16*)outp)[(size_t)node * 128 + col] = (u16)f2bf(y);
            }
        }
    }
}

extern "C" void kernel_launch(void* const* d_in, const int* in_sizes, int n_in,
                              void* d_out, int out_size, void* d_ws, size_t ws_size,
                              hipStream_t stream) {
    const float* x   = (const float*)d_in[0];
    const int*   ei  = (const int*)d_in[1];
    const float* W1  = (const float*)d_in[2];
    const float* b1  = (const float*)d_in[3];
    const float* g1  = (const float*)d_in[4];
    const float* bt1 = (const float*)d_in[5];
    const float* W2  = (const float*)d_in[6];
    const float* b2  = (const float*)d_in[7];
    const float* g2  = (const float*)d_in[8];
    const float* bt2 = (const float*)d_in[9];

    const int* src = ei;
    const int* dst = ei + NE;

    // workspace layout (4B units)
    const int NP = (NN + 255) & ~255;
    int*   gcnt   = (int*)d_ws;                     // 256
    int2*  off2   = (int2*)(gcnt + 256);            // NN int2 (0.8 MB)
    float* dinv   = (float*)(off2 + NP);            // NP (0.4 MB)
    int*   csr    = (int*)(dinv + NP);              // NBKT*CAP ints (9.6 MB)
    u32*   binned = (u32*)(csr + NBKT * CAP);       // NBKT*CAP u32 (9.6 MB)
    u16*   xb     = (u16*)(binned + NBKT * CAP);    // NN*64 bf16 (12.8 MB)
    u16*   h1     = xb + (size_t)NN * 64;           // NN*128 bf16 (25.6 MB)
    u16*   WT1    = h1 + (size_t)NN * 128;          // 128*64 bf16
    u16*   WT2    = WT1 + 128 * 64;                 // 128*128 bf16

    // ---- prep (also zeroes gcnt) + build CSR (+cvt fused into kB_fill) ----
    k_prep<<<(24576 + NBKT + 255) / 256, 256, 0, stream>>>(W1, W2, WT1, WT2, gcnt);
    kA_bin<<<ABLK, 256, 0, stream>>>(src, dst, gcnt, binned);
    kB_fill<<<NBKT, 256, 0, stream>>>(binned, gcnt, off2, dinv, csr, x, xb);

    // ---- layer 1 fused: agg(x') + gemm + LN + ReLU + prescale -> h1 (ws) ---
    k_fused<64, false, true><<<(NN + 63) / 64, 256, 0, stream>>>(
        xb, off2, csr, dinv, WT1, b1, g1, bt1, h1);

    // ---- layer 2 fused: agg(h1') + gemm + LN + ReLU -> out (fp32) ----------
    k_fused<128, true, false><<<(NN + 63) / 64, 256, 0, stream>>>(
        h1, off2, csr, dinv, WT2, b2, g2, bt2, d_out);
}

// Round 14
// 201.156 us; speedup vs baseline: 1.1759x; 1.1759x over previous
//
#include <hip/hip_runtime.h>

#define NN 100000
#define NE 1600000
#define NBKT 196                 // ceil(NN / 512)
#define CAP 12288                // per-bucket csr capacity (max ~8600 expected)
#define EPB 2048                 // edges per block in binning pass
#define ABLK ((NE + EPB - 1) / EPB)  // 782
typedef unsigned short u16;
typedef unsigned int u32;

typedef __attribute__((ext_vector_type(8))) short short8v;
typedef __attribute__((ext_vector_type(4))) float f32x4;

// ---- bf16 helpers (round-to-nearest-even) ----
__device__ __forceinline__ u32 f2bf(float f) {
    u32 u = __float_as_uint(f);
    return (u + 0x7fffu + ((u >> 16) & 1u)) >> 16;
}
__device__ __forceinline__ u32 pack2(float a, float b) {
    return f2bf(a) | (f2bf(b) << 16);
}
__device__ __forceinline__ void accum8(float* a, uint4 u, float w) {
    a[0] += __uint_as_float(u.x << 16) * w;
    a[1] += __uint_as_float(u.x & 0xffff0000u) * w;
    a[2] += __uint_as_float(u.y << 16) * w;
    a[3] += __uint_as_float(u.y & 0xffff0000u) * w;
    a[4] += __uint_as_float(u.z << 16) * w;
    a[5] += __uint_as_float(u.z & 0xffff0000u) * w;
    a[6] += __uint_as_float(u.w << 16) * w;
    a[7] += __uint_as_float(u.w & 0xffff0000u) * w;
}

// ---------------- bin edges into fixed-capacity buckets ---------------------
__global__ __launch_bounds__(256) void kA_bin(const int* __restrict__ src,
                                              const int* __restrict__ dst,
                                              int* __restrict__ gcnt,
                                              u32* __restrict__ binned) {
    __shared__ int bc[NBKT];
    __shared__ int cbase[NBKT];
    const int tid = threadIdx.x;
    for (int i = tid; i < NBKT; i += 256) bc[i] = 0;
    __syncthreads();
    const int e0 = blockIdx.x * EPB;
#pragma unroll
    for (int i = 0; i < EPB / 256; ++i) {
        const int e = e0 + i * 256 + tid;
        if (e < NE) atomicAdd(&bc[dst[e] >> 9], 1);
    }
    __syncthreads();
    for (int i = tid; i < NBKT; i += 256)
        cbase[i] = bc[i] ? atomicAdd(&gcnt[i], bc[i]) : 0;
    __syncthreads();
    for (int i = tid; i < NBKT; i += 256) bc[i] = 0;  // reuse as cursor
    __syncthreads();
#pragma unroll
    for (int i = 0; i < EPB / 256; ++i) {
        const int e = e0 + i * 256 + tid;
        if (e < NE) {
            const int d = dst[e];
            const int bkt = d >> 9;
            const int p = atomicAdd(&bc[bkt], 1);
            binned[bkt * CAP + cbase[bkt] + p] = ((u32)src[e] << 9) | (u32)(d & 511);
        }
    }
}

// ---------------- per-bucket: counts -> off2/dinv, fill csr, cvt x ----------
__global__ __launch_bounds__(256) void kB_fill(const u32* __restrict__ binned,
                                               const int* __restrict__ gcnt,
                                               int2* __restrict__ off2,
                                               float* __restrict__ dinv,
                                               int* __restrict__ csr,
                                               const float* __restrict__ x,
                                               u16* __restrict__ xb) {
    __shared__ int lcnt[512];
    __shared__ int lpos[512];
    __shared__ float sdinv[512];
    __shared__ int ws[4];
    const int b = blockIdx.x;
    const int tid = threadIdx.x;
    const int cnt = gcnt[b];
    const int base0 = b * CAP;
    const int node0 = b << 9;
    lcnt[tid] = 0;
    lcnt[tid + 256] = 0;
    __syncthreads();
    for (int e = tid; e < cnt; e += 256)
        atomicAdd(&lcnt[binned[base0 + e] & 511], 1);
    __syncthreads();
    const int c0 = lcnt[tid * 2], c1 = lcnt[tid * 2 + 1];
    const int s = c0 + c1;
    const int lane = tid & 63, w = tid >> 6;
    int incl = s;
#pragma unroll
    for (int o = 1; o < 64; o <<= 1) {
        const int u = __shfl_up(incl, o);
        if (lane >= o) incl += u;
    }
    if (lane == 63) ws[w] = incl;
    __syncthreads();
    int base = incl - s;
    for (int i = 0; i < w; ++i) base += ws[i];
    lpos[tid * 2] = base;
    lpos[tid * 2 + 1] = base + c0;
    const float d0 = rsqrtf(1.0f + (float)c0);
    const float d1 = rsqrtf(1.0f + (float)c1);
    sdinv[tid * 2] = d0;
    sdinv[tid * 2 + 1] = d1;
    const int n0 = node0 + tid * 2;
    if (n0 < NN) {
        off2[n0] = make_int2(base0 + base, base0 + base + c0);
        dinv[n0] = d0;
    }
    if (n0 + 1 < NN) {
        off2[n0 + 1] = make_int2(base0 + base + c0, base0 + base + c0 + c1);
        dinv[n0 + 1] = d1;
    }
    __syncthreads();
    for (int e = tid; e < cnt; e += 256) {
        const u32 u = binned[base0 + e];
        const int p = atomicAdd(&lpos[u & 511], 1);
        csr[base0 + p] = (int)(u >> 9);
    }
    // ---- fused cvt: x rows of this bucket -> bf16 pre-scaled by dinv ----
    const int nmax = min(512, NN - node0);
    for (int gi = tid; gi < nmax * 8; gi += 256) {
        const int nl = gi >> 3, ch = gi & 7;
        const float dr = sdinv[nl];
        const size_t xo = (size_t)(node0 + nl) * 64 + ch * 8;
        const float4 v0 = *(const float4*)&x[xo];
        const float4 v1 = *(const float4*)&x[xo + 4];
        uint4 o;
        o.x = pack2(v0.x * dr, v0.y * dr); o.y = pack2(v0.z * dr, v0.w * dr);
        o.z = pack2(v1.x * dr, v1.y * dr); o.w = pack2(v1.z * dr, v1.w * dr);
        *(uint4*)&xb[xo] = o;
    }
}

// ---------------- prep: WT1, WT2 (transposed bf16) + gcnt zero --------------
__global__ __launch_bounds__(256) void k_prep(const float* __restrict__ W1,
                                              const float* __restrict__ W2,
                                              u16* __restrict__ WT1,
                                              u16* __restrict__ WT2,
                                              int* __restrict__ gcnt) {
    const int i = blockIdx.x * 256 + threadIdx.x;
    if (i < 8192) {                       // W1: 64x128 -> WT1[128][64]
        const int k = i >> 7, c = i & 127;
        WT1[c * 64 + k] = (u16)f2bf(W1[i]);
    } else if (i < 24576) {               // W2: 128x128 -> WT2[128][128]
        const int i2 = i - 8192;
        const int k = i2 >> 7, c = i2 & 127;
        WT2[c * 128 + k] = (u16)f2bf(W2[i2]);
    } else if (i < 24576 + NBKT) {
        gcnt[i - 24576] = 0;
    }
}

// ---------------- fused: gather + MFMA + bias + LN + ReLU -------------------
// Block = 32 nodes, 4 waves. Phase 1: waves CLAIM nodes dynamically (LDS
// atomic counter) -> 3-deep pipelined gather -> XOR-swizzled LDS row.
// Phase 2: 32x128xK MFMA (wave owns 32 cols), cross-wave LN stats via LDS.
template<int K, bool FP32OUT, bool PRESCALE>
__global__ __launch_bounds__(256) void k_fused(const u16* __restrict__ A,
                                               const int2* __restrict__ off2,
                                               const int* __restrict__ csr,
                                               const float* __restrict__ dinv,
                                               const u16* __restrict__ WT,
                                               const float* __restrict__ bias,
                                               const float* __restrict__ g,
                                               const float* __restrict__ bt,
                                               void* __restrict__ outp) {
    constexpr int RB = K * 2;          // staged row bytes
    constexpr int SUBS = 512 / K;      // 8 (K=64) or 4 (K=128)
    constexpr int LSH = (K == 64) ? 7 : 8;
    __shared__ u16 As[32 * K];
    __shared__ float s1s[4][32];
    __shared__ float s2s[4][32];
    __shared__ int claim;
    const int tid = threadIdx.x;
    const int wv = tid >> 6, lane = tid & 63;
    const int sub = lane / (64 / SUBS);
    const int l = lane & (64 / SUBS - 1);
    const char* Ab = (const char*)A + ((u32)l << 4);
    const int nodeBase = blockIdx.x * 32;   // NN % 32 == 0

    if (tid == 0) claim = 0;
    __syncthreads();

    // ---- phase 1: gather nodes via dynamic claiming ----
    int i;
    if (lane == 0) i = atomicAdd(&claim, 1);
    i = __builtin_amdgcn_readfirstlane(i);
    while (i < 32) {
        const int node = nodeBase + i;
        const float di = dinv[node];
        float a[8] = {};
        {
            const uint4 u = *(const uint4*)(Ab + ((u32)node << LSH));
            accum8(a, u, (sub == 0) ? 1.0f : 0.0f);
        }
        const int2 oe = off2[node];
        int base = oe.x;
        const int e1 = oe.y;
        u32 iA = 0, iB = 0, iC = 0;
        float vA = 0.f, vB = 0.f, vC = 0.f;
        if (base < e1) {
            const int eA = base + sub, eB = eA + SUBS, eC = eA + 2 * SUBS;
            iA = (u32)csr[min(eA, e1 - 1)];
            iB = (u32)csr[min(eB, e1 - 1)];
            iC = (u32)csr[min(eC, e1 - 1)];
            vA = (eA < e1) ? 1.f : 0.f;
            vB = (eB < e1) ? 1.f : 0.f;
            vC = (eC < e1) ? 1.f : 0.f;
        }
        while (base < e1) {
            const uint4 uA = *(const uint4*)(Ab + (iA << LSH));
            const uint4 uB = *(const uint4*)(Ab + (iB << LSH));
            const uint4 uC = *(const uint4*)(Ab + (iC << LSH));
            const float wA = vA, wB = vB, wC = vC;
            base += 3 * SUBS;
            if (base < e1) {
                const int eA = base + sub, eB = eA + SUBS, eC = eA + 2 * SUBS;
                iA = (u32)csr[min(eA, e1 - 1)];
                iB = (u32)csr[min(eB, e1 - 1)];
                iC = (u32)csr[min(eC, e1 - 1)];
                vA = (eA < e1) ? 1.f : 0.f;
                vB = (eB < e1) ? 1.f : 0.f;
                vC = (eC < e1) ? 1.f : 0.f;
            }
            accum8(a, uA, wA);
            accum8(a, uB, wB);
            accum8(a, uC, wC);
        }
#pragma unroll
        for (int t = 0; t < 8; ++t)
#pragma unroll
            for (int o = 64 / SUBS; o < 64; o <<= 1)
                a[t] += __shfl_xor(a[t], o);
        if (sub == 0) {
            uint4 o;
            o.x = pack2(a[0] * di, a[1] * di); o.y = pack2(a[2] * di, a[3] * di);
            o.z = pack2(a[4] * di, a[5] * di); o.w = pack2(a[6] * di, a[7] * di);
            *(uint4*)((char*)As + i * RB + (((u32)l << 4) ^ ((u32)(i & 7) << 4))) = o;
        }
        if (lane == 0) i = atomicAdd(&claim, 1);
        i = __builtin_amdgcn_readfirstlane(i);
    }
    __syncthreads();

    // ---- phase 2: 32 x 128 x K MFMA; wave owns cols [wv*32, wv*32+32) ----
    const int lr = lane & 15, kg = lane >> 4;
    short8v af[2][K / 32];
#pragma unroll
    for (int rt = 0; rt < 2; ++rt)
#pragma unroll
        for (int kk = 0; kk < K / 32; ++kk)
            af[rt][kk] = *(const short8v*)((const char*)As + (rt * 16 + lr) * RB +
                                           ((u32)(kk * 64 + kg * 16) ^ ((u32)(lr & 7) << 4)));
    f32x4 acc[2][2];
    float bv[2], gv[2], tv[2];
#pragma unroll
    for (int nt = 0; nt < 2; ++nt) {
        acc[0][nt] = (f32x4){0.f, 0.f, 0.f, 0.f};
        acc[1][nt] = (f32x4){0.f, 0.f, 0.f, 0.f};
        const int col = wv * 32 + nt * 16 + lr;
        short8v bf[K / 32];
#pragma unroll
        for (int kk = 0; kk < K / 32; ++kk)
            bf[kk] = *(const short8v*)&WT[col * K + kk * 32 + kg * 8];
#pragma unroll
        for (int rt = 0; rt < 2; ++rt)
#pragma unroll
            for (int kk = 0; kk < K / 32; ++kk)
                acc[rt][nt] = __builtin_amdgcn_mfma_f32_16x16x32_bf16(
                    af[rt][kk], bf[kk], acc[rt][nt], 0, 0, 0);
        bv[nt] = bias[col]; gv[nt] = g[col]; tv[nt] = bt[col];
    }

    // ---- bias + per-wave partial LN stats over this wave's 32 cols ----
    float s1[2][4] = {};
    float s2[2][4] = {};
#pragma unroll
    for (int rt = 0; rt < 2; ++rt)
#pragma unroll
        for (int nt = 0; nt < 2; ++nt)
#pragma unroll
            for (int j = 0; j < 4; ++j) {
                const float v = acc[rt][nt][j] + bv[nt];
                acc[rt][nt][j] = v;
                s1[rt][j] += v;
                s2[rt][j] += v * v;
            }
#pragma unroll
    for (int rt = 0; rt < 2; ++rt)
#pragma unroll
        for (int j = 0; j < 4; ++j)
#pragma unroll
            for (int o = 1; o < 16; o <<= 1) {
                s1[rt][j] += __shfl_xor(s1[rt][j], o);
                s2[rt][j] += __shfl_xor(s2[rt][j], o);
            }
    if (lr == 0) {
#pragma unroll
        for (int rt = 0; rt < 2; ++rt)
#pragma unroll
            for (int j = 0; j < 4; ++j) {
                s1s[wv][rt * 16 + kg * 4 + j] = s1[rt][j];
                s2s[wv][rt * 16 + kg * 4 + j] = s2[rt][j];
            }
    }
    __syncthreads();

    // ---- cross-wave LN + ReLU + write ----
#pragma unroll
    for (int rt = 0; rt < 2; ++rt)
#pragma unroll
        for (int j = 0; j < 4; ++j) {
            const int row = rt * 16 + kg * 4 + j;
            const float t1 = s1s[0][row] + s1s[1][row] + s1s[2][row] + s1s[3][row];
            const float t2 = s2s[0][row] + s2s[1][row] + s2s[2][row] + s2s[3][row];
            const float mu = t1 * (1.0f / 128.0f);
            const float var = t2 * (1.0f / 128.0f) - mu * mu;
            const float rs = rsqrtf(var + 1e-5f);
            const int node = nodeBase + row;
            const float dr = PRESCALE ? dinv[node] : 1.0f;
#pragma unroll
            for (int nt = 0; nt < 2; ++nt) {
                const float y = fmaxf((acc[rt][nt][j] - mu) * rs * gv[nt] + tv[nt], 0.f) * dr;
                const int col = wv * 32 + nt * 16 + lr;
                if constexpr (FP32OUT)
                    ((float*)outp)[(size_t)node * 128 + col] = y;
                else
                    ((u16*)outp)[(size_t)node * 128 + col] = (u16)f2bf(y);
            }
        }
}

extern "C" void kernel_launch(void* const* d_in, const int* in_sizes, int n_in,
                              void* d_out, int out_size, void* d_ws, size_t ws_size,
                              hipStream_t stream) {
    const float* x   = (const float*)d_in[0];
    const int*   ei  = (const int*)d_in[1];
    const float* W1  = (const float*)d_in[2];
    const float* b1  = (const float*)d_in[3];
    const float* g1  = (const float*)d_in[4];
    const float* bt1 = (const float*)d_in[5];
    const float* W2  = (const float*)d_in[6];
    const float* b2  = (const float*)d_in[7];
    const float* g2  = (const float*)d_in[8];
    const float* bt2 = (const float*)d_in[9];

    const int* src = ei;
    const int* dst = ei + NE;

    // workspace layout (4B units)
    const int NP = (NN + 255) & ~255;
    int*   gcnt   = (int*)d_ws;                     // 256
    int2*  off2   = (int2*)(gcnt + 256);            // NN int2 (0.8 MB)
    float* dinv   = (float*)(off2 + NP);            // NP (0.4 MB)
    int*   csr    = (int*)(dinv + NP);              // NBKT*CAP ints (9.6 MB)
    u32*   binned = (u32*)(csr + NBKT * CAP);       // NBKT*CAP u32 (9.6 MB)
    u16*   xb     = (u16*)(binned + NBKT * CAP);    // NN*64 bf16 (12.8 MB)
    u16*   h1     = xb + (size_t)NN * 64;           // NN*128 bf16 (25.6 MB)
    u16*   WT1    = h1 + (size_t)NN * 128;          // 128*64 bf16
    u16*   WT2    = WT1 + 128 * 64;                 // 128*128 bf16

    // ---- prep (also zeroes gcnt) + build CSR (+cvt fused into kB_fill) ----
    k_prep<<<(24576 + NBKT + 255) / 256, 256, 0, stream>>>(W1, W2, WT1, WT2, gcnt);
    kA_bin<<<ABLK, 256, 0, stream>>>(src, dst, gcnt, binned);
    kB_fill<<<NBKT, 256, 0, stream>>>(binned, gcnt, off2, dinv, csr, x, xb);

    // ---- layer 1 fused: agg(x') + gemm + LN + ReLU + prescale -> h1 (ws) ---
    k_fused<64, false, true><<<NN / 32, 256, 0, stream>>>(
        xb, off2, csr, dinv, WT1, b1, g1, bt1, h1);

    // ---- layer 2 fused: agg(h1') + gemm + LN + ReLU -> out (fp32) ----------
    k_fused<128, true, false><<<NN / 32, 256, 0, stream>>>(
        h1, off2, csr, dinv, WT2, b2, g2, bt2, d_out);
}